// Round 8
// baseline (46975.772 us; speedup 1.0000x reference)
//
#include <hip/hip_runtime.h>
#include <math.h>

// ESN forward: x_{t+1} = 0.1*x_t + 0.9*tanh(W_in @ u_t + W @ x_t); y_t = Wout @ x_{t+1}
// W sparse (5%) -> padded ELL in ws. 64 cooperative WGs x 512, fence-free.
// R8: R4's merged detect+data exchange (tagged u64, owner-exclusive lines,
// no flags / no vmcnt / no release chain) with BOUNDED polling: each thread
// spins on ONE word, one-shot loads the other 7, masked retry for stragglers.
// ONE __syncthreads per step; readout done by wave 0 alone (no barrier),
// hidden under the other waves' next-step poll.

#define NX 4096
#define NU 128
#define NY 64
#define TSTEPS 4096
#define CAP 352            // padded nnz per row (mean 204.8, sd 13.9)
#define WGS 64
#define TPB 512
#define RPW (NX / WGS)     // 64 rows per workgroup
#define TPR (TPB / RPW)    // 8 threads per row
#define EPT (CAP / TPR)    // 44 ELL entries per thread -> 22 int4
#define UPT (NU / TPR)     // 16 W_in entries per thread
#define XW  (NX / TPB)     // 8 packed words per thread

typedef unsigned long long u64;

// --- Kernel 1: deterministic dense->ELL compaction, one block per row ---
__global__ void build_ell_kernel(const float* __restrict__ W, int2* __restrict__ ell) {
    const int r = blockIdx.x;
    const int tid = threadIdx.x;
    const int wv = tid >> 6, ln = tid & 63;
    __shared__ int wave_tot[4];
    __shared__ int base;
    if (tid == 0) base = 0;
    __syncthreads();
    const float* row = W + (size_t)r * NX;
    int2* out = ell + (size_t)r * CAP;
    for (int chunk = 0; chunk < NX; chunk += 256) {
        float w = row[chunk + tid];
        bool p = (w != 0.0f);
        unsigned long long m = __ballot(p);
        int lp = (int)__popcll(m & ((1ull << ln) - 1ull));
        if (ln == 63) wave_tot[wv] = lp + (p ? 1 : 0);
        __syncthreads();
        int wbase = 0;
        #pragma unroll
        for (int i = 0; i < 4; ++i)
            if (i < wv) wbase += wave_tot[i];
        int tot = wave_tot[0] + wave_tot[1] + wave_tot[2] + wave_tot[3];
        if (p) {
            int o = base + wbase + lp;
            if (o < CAP) out[o] = make_int2(chunk + tid, __float_as_int(w));
        }
        __syncthreads();
        if (tid == 0) base += tot;
        __syncthreads();
    }
    for (int o = base + tid; o < CAP; o += 256) out[o] = make_int2(0, 0);
}

__device__ __forceinline__ u64 ld_agent(const u64* p) {
    return __hip_atomic_load(p, __ATOMIC_RELAXED, __HIP_MEMORY_SCOPE_AGENT);
}

// stage tagged state (epoch ep, buffer xs) into LDS xc. No barrier inside.
__device__ __forceinline__ void stage_state(const u64* xs, float* xc,
                                            int tid, unsigned ep) {
    // 1-word spin: per-wave coalesced, writer-exclusive lines
    u64 v0;
    do { v0 = ld_agent(xs + tid); } while ((unsigned)(v0 >> 32) != ep);
    xc[tid] = __uint_as_float((unsigned)v0);
    // one-shot bulk for the remaining 7 words
    u64 v[XW];
    #pragma unroll
    for (int j = 1; j < XW; ++j) v[j] = ld_agent(xs + tid + TPB * j);
    unsigned miss = 0;
    #pragma unroll
    for (int j = 1; j < XW; ++j)
        if ((unsigned)(v[j] >> 32) != ep) miss |= 1u << j;
    while (miss) {                       // rare: straggler writer's lines
        #pragma unroll
        for (int j = 1; j < XW; ++j)
            if (miss & (1u << j)) {
                v[j] = ld_agent(xs + tid + TPB * j);
                if ((unsigned)(v[j] >> 32) == ep) miss &= ~(1u << j);
            }
    }
    #pragma unroll
    for (int j = 1; j < XW; ++j)
        xc[tid + TPB * j] = __uint_as_float((unsigned)v[j]);
}

// --- Kernel 2: cooperative sequential recurrence ---
__global__ void __launch_bounds__(TPB, 1) esn_kernel(
    const float* __restrict__ UT, const float* __restrict__ x0,
    const float* __restrict__ Win, const float* __restrict__ Wout,
    const int2* __restrict__ ell, u64* __restrict__ xbuf,  // [2][NX] tagged
    float* __restrict__ Y)
{
    __shared__ __align__(16) float xl[2][NX];

    const int tid = threadIdx.x;
    const int wg  = blockIdx.x;              // 0..63
    const int grp = tid >> 3;                // row group within WG (0..63)
    const int ln  = tid & 7;                 // lane within row group
    const int r   = wg * RPW + grp;          // global row this 8-thread group owns

    const float4* winrow = (const float4*)(Win + (size_t)r * NU + ln * UPT);
    const int4*   ellrow = (const int4*)  (ell + (size_t)r * CAP + ln * EPT);
    const float*  woutrow = Wout + (size_t)wg * NX;

    for (int t = 0; t < TSTEPS; ++t) {
        float* xc = xl[t & 1];

        // ---- x-independent partial: acc = Win[r,:] @ u_t (L1/L2-cached) ----
        float acc = 0.0f;
        {
            const float4* u4 = (const float4*)(UT + (size_t)t * NU + ln * UPT);
            #pragma unroll
            for (int i = 0; i < UPT / 4; ++i) {
                float4 w = winrow[i], u = u4[i];
                acc += w.x * u.x + w.y * u.y + w.z * u.z + w.w * u.w;
            }
        }

        // ---- stage x_t into LDS (detect==data, single round trip) ----
        if (t == 0) {
            const float4* xs4 = (const float4*)x0;
            float4* xl4 = (float4*)xc;
            #pragma unroll
            for (int i = tid; i < NX / 4; i += TPB) xl4[i] = xs4[i];
        } else {
            stage_state(xbuf + (size_t)(t & 1) * NX, xc, tid, (unsigned)t);
        }
        __syncthreads();   // the ONLY barrier in the step

        // ---- acc += W[r,:] @ x_t (ELL int4 L2 stream, LDS gather) ----
        #pragma unroll 4
        for (int i = 0; i < EPT / 2; ++i) {
            int4 cv = ellrow[i];   // two (col,val) pairs
            acc += __int_as_float(cv.y) * xc[cv.x]
                 + __int_as_float(cv.w) * xc[cv.z];
        }
        acc += __shfl_down(acc, 4, 8);
        acc += __shfl_down(acc, 2, 8);
        acc += __shfl_down(acc, 1, 8);

        // ---- publish x_{t+1}: tagged u64, 64 B per wave, owner-exclusive ----
        if (ln == 0) {
            float xn = 0.1f * xc[r] + 0.9f * tanhf(acc);
            u64 packed = ((u64)(unsigned)(t + 1) << 32) | (u64)__float_as_uint(xn);
            __hip_atomic_store(xbuf + (size_t)((t + 1) & 1) * NX + r, packed,
                               __ATOMIC_RELAXED, __HIP_MEMORY_SCOPE_AGENT);
        }

        // ---- readout Y[t-1] = Wout[wg] . x_t : wave 0 only, no barrier;
        //      waves 1-7 move straight into the next step's poll ----
        if (t > 0 && tid < 64) {
            float a = 0.0f;
            for (int i = tid; i < NX; i += 64) a += woutrow[i] * xc[i];
            #pragma unroll
            for (int off = 32; off; off >>= 1) a += __shfl_down(a, off, 64);
            if (tid == 0) Y[(size_t)(t - 1) * NY + wg] = a;
        }
    }

    // ---- final: stage x_T (epoch TSTEPS, slot 0), emit Y[T-1] ----
    {
        float* xc = xl[0];
        stage_state(xbuf + (size_t)(TSTEPS & 1) * NX, xc, tid, (unsigned)TSTEPS);
        __syncthreads();
        if (tid < 64) {
            float a = 0.0f;
            for (int i = tid; i < NX; i += 64) a += woutrow[i] * xc[i];
            #pragma unroll
            for (int off = 32; off; off >>= 1) a += __shfl_down(a, off, 64);
            if (tid == 0) Y[(size_t)(TSTEPS - 1) * NY + wg] = a;
        }
    }
}

extern "C" void kernel_launch(void* const* d_in, const int* in_sizes, int n_in,
                              void* d_out, int out_size, void* d_ws, size_t ws_size,
                              hipStream_t stream) {
    const float* UT   = (const float*)d_in[0];  // [T, NU]
    const float* x0   = (const float*)d_in[1];  // [NX]
    const float* Win  = (const float*)d_in[2];  // [NX, NU]
    const float* W    = (const float*)d_in[3];  // [NX, NX]
    const float* Wout = (const float*)d_in[4];  // [NY, NX]
    float* Y = (float*)d_out;                   // [T*NY]

    char* ws = (char*)d_ws;
    u64*  xbuf = (u64*)ws;                      // 2*NX tagged words = 64 KB
    int2* ell  = (int2*)(ws + 65536);           // NX*CAP*8 = 11,534,336 B

    build_ell_kernel<<<dim3(NX), dim3(256), 0, stream>>>(W, ell);

    void* args[] = { (void*)&UT, (void*)&x0, (void*)&Win, (void*)&Wout,
                     (void*)&ell, (void*)&xbuf, (void*)&Y };
    hipLaunchCooperativeKernel((const void*)esn_kernel, dim3(WGS), dim3(TPB),
                               args, 0, stream);
}

// Round 11
// 43753.156 us; speedup vs baseline: 1.0737x; 1.0737x over previous
//
#include <hip/hip_runtime.h>
#include <math.h>

// ESN forward: x_{t+1} = 0.1*x_t + 0.9*tanh(W_in @ u_t + W @ x_t); y_t = Wout @ x_{t+1}
// W sparse (5%) -> padded ELL in ws. 64 cooperative WGs x 512, fence-free.
// R11 = R9/R10 (two container-level failures, kernel audited 3x: poll monotone,
// single-writer flags, non-divergent barriers, parity buffer overwrite-safe,
// VGPR within lb(512,2) budget) + s_sleep(1) backoff in poll loops to cut
// spin-probe fabric pressure (the only identifiable node-stress mechanism).
//   1. ELL slice lives in REGISTERS across all 4096 steps (loaded once)
//   2. per-WAVE release flags (rows sc1-stored -> own vmcnt(0) -> flag store);
//      readers spin on ONE flag word each (512 words, write-once lines)
//   3. two __syncthreads per step; readout by wave 7 only, no extra barrier

#define NX 4096
#define NU 128
#define NY 64
#define TSTEPS 4096
#define CAP 352            // padded nnz per row (mean 204.8, sd 13.9)
#define WGS 64
#define TPB 512
#define NWAVE (TPB / 64)   // 8 waves
#define RPW (NX / WGS)     // 64 rows per workgroup
#define TPR (TPB / RPW)    // 8 threads per row
#define EPT (CAP / TPR)    // 44 ELL entries per thread -> 22 int4
#define UPT (NU / TPR)     // 16 W_in entries per thread
#define XW  (NX / 2 / TPB) // 4 u64 bulk words per thread

typedef unsigned long long u64;

// --- Kernel 1: dense->ELL compaction (one block per row) + flag init ---
__global__ void build_ell_kernel(const float* __restrict__ W, int2* __restrict__ ell,
                                 int* __restrict__ flags) {
    const int r = blockIdx.x;
    const int tid = threadIdx.x;
    if (r == 0)
        for (int i = tid; i < WGS * NWAVE; i += 256) flags[i] = 0;
    const int wv = tid >> 6, ln = tid & 63;
    __shared__ int wave_tot[4];
    __shared__ int base;
    if (tid == 0) base = 0;
    __syncthreads();
    const float* row = W + (size_t)r * NX;
    int2* out = ell + (size_t)r * CAP;
    for (int chunk = 0; chunk < NX; chunk += 256) {
        float w = row[chunk + tid];
        bool p = (w != 0.0f);
        unsigned long long m = __ballot(p);
        int lp = (int)__popcll(m & ((1ull << ln) - 1ull));
        if (ln == 63) wave_tot[wv] = lp + (p ? 1 : 0);
        __syncthreads();
        int wbase = 0;
        #pragma unroll
        for (int i = 0; i < 4; ++i)
            if (i < wv) wbase += wave_tot[i];
        int tot = wave_tot[0] + wave_tot[1] + wave_tot[2] + wave_tot[3];
        if (p) {
            int o = base + wbase + lp;
            if (o < CAP) out[o] = make_int2(chunk + tid, __float_as_int(w));
        }
        __syncthreads();
        if (tid == 0) base += tot;
        __syncthreads();
    }
    for (int o = base + tid; o < CAP; o += 256) out[o] = make_int2(0, 0);
}

__device__ __forceinline__ u64 ld_agent64(const u64* p) {
    return __hip_atomic_load(p, __ATOMIC_RELAXED, __HIP_MEMORY_SCOPE_AGENT);
}

// --- Kernel 2: cooperative sequential recurrence ---
__global__ void __launch_bounds__(TPB, 2) esn_kernel(
    const float* __restrict__ UT, const float* __restrict__ x0,
    const float* __restrict__ Win, const float* __restrict__ Wout,
    const int2* __restrict__ ell, float* __restrict__ xbuf,  // [2][NX] fp32
    int* __restrict__ flags,                                  // [64][8] per-wave
    float* __restrict__ Y)
{
    __shared__ __align__(16) float xl[2][NX];

    const int tid = threadIdx.x;
    const int wg  = blockIdx.x;              // 0..63
    const int grp = tid >> 3;                // row group within WG (0..63)
    const int ln  = tid & 7;                 // lane within row group
    const int r   = wg * RPW + grp;          // global row this 8-thread group owns
    const int wave = tid >> 6;

    const float4* winrow = (const float4*)(Win + (size_t)r * NU + ln * UPT);
    const float*  woutrow = Wout + (size_t)wg * NX;

    // ---- ELL slice -> registers, ONCE (x-independent, reused 4096 steps) ----
    int4 e[EPT / 2];
    {
        const int4* ellrow = (const int4*)(ell + (size_t)r * CAP + ln * EPT);
        #pragma unroll
        for (int i = 0; i < EPT / 2; ++i) e[i] = ellrow[i];
    }

    for (int t = 0; t < TSTEPS; ++t) {
        float* xc = xl[t & 1];

        // ---- x-independent partial: acc = Win[r,:] @ u_t (L1/L2-cached) ----
        float acc = 0.0f;
        {
            const float4* u4 = (const float4*)(UT + (size_t)t * NU + ln * UPT);
            #pragma unroll
            for (int i = 0; i < UPT / 4; ++i) {
                float4 w = winrow[i], u = u4[i];
                acc += w.x * u.x + w.y * u.y + w.z * u.z + w.w * u.w;
            }
        }

        // ---- stage x_t into LDS: bounded flag poll (1 word/thread), then bulk ----
        if (t == 0) {
            const float4* xs4 = (const float4*)x0;
            float4* xl4 = (float4*)xc;
            #pragma unroll
            for (int i = tid; i < NX / 4; i += TPB) xl4[i] = xs4[i];
            __syncthreads();
        } else {
            // each thread spins on ONE per-wave flag word (write-once lines),
            // with s_sleep backoff to keep probe traffic gentle
            int v = __hip_atomic_load(flags + tid, __ATOMIC_RELAXED,
                                      __HIP_MEMORY_SCOPE_AGENT);
            while (v < t) {
                __builtin_amdgcn_s_sleep(1);
                v = __hip_atomic_load(flags + tid, __ATOMIC_RELAXED,
                                      __HIP_MEMORY_SCOPE_AGENT);
            }
            __syncthreads();                     // barrier 1: all flags confirmed
            const u64* xs = (const u64*)(xbuf + (size_t)(t & 1) * NX);
            u64 v8[XW];
            #pragma unroll
            for (int j = 0; j < XW; ++j) v8[j] = ld_agent64(xs + tid + TPB * j);
            u64* xc8 = (u64*)xc;
            #pragma unroll
            for (int j = 0; j < XW; ++j) xc8[tid + TPB * j] = v8[j];
            __syncthreads();                     // barrier 2: LDS x_t complete
        }

        // ---- acc += W[r,:] @ x_t (ELL from REGISTERS, gather from LDS) ----
        #pragma unroll
        for (int i = 0; i < EPT / 2; ++i) {
            int4 cv = e[i];   // two (col,val) pairs
            acc += __int_as_float(cv.y) * xc[cv.x]
                 + __int_as_float(cv.w) * xc[cv.z];
        }
        acc += __shfl_down(acc, 4, 8);
        acc += __shfl_down(acc, 2, 8);
        acc += __shfl_down(acc, 1, 8);

        // ---- publish x_{t+1} rows (sc1), per-WAVE release flag ----
        if (ln == 0) {
            float xn = 0.1f * xc[r] + 0.9f * tanhf(acc);
            __hip_atomic_store(xbuf + (size_t)((t + 1) & 1) * NX + r, xn,
                               __ATOMIC_RELAXED, __HIP_MEMORY_SCOPE_AGENT);
        }
        asm volatile("s_waitcnt vmcnt(0)" ::: "memory");   // this wave's rows acked
        if ((tid & 63) == 0)
            __hip_atomic_store(flags + wg * NWAVE + wave, t + 1,
                               __ATOMIC_RELAXED, __HIP_MEMORY_SCOPE_AGENT);

        // ---- readout Y[t-1] = Wout[wg] . x_t : wave 7 only, no barrier ----
        if (t > 0 && wave == NWAVE - 1) {
            const int lane = tid & 63;
            float a = 0.0f;
            for (int i = lane; i < NX; i += 64) a += woutrow[i] * xc[i];
            #pragma unroll
            for (int off = 32; off; off >>= 1) a += __shfl_down(a, off, 64);
            if (lane == 0) Y[(size_t)(t - 1) * NY + wg] = a;
        }
    }

    // ---- final: stage x_T (epoch TSTEPS, slot 0), emit Y[T-1] ----
    {
        float* xc = xl[0];
        int v = __hip_atomic_load(flags + tid, __ATOMIC_RELAXED,
                                  __HIP_MEMORY_SCOPE_AGENT);
        while (v < TSTEPS) {
            __builtin_amdgcn_s_sleep(1);
            v = __hip_atomic_load(flags + tid, __ATOMIC_RELAXED,
                                  __HIP_MEMORY_SCOPE_AGENT);
        }
        __syncthreads();
        const u64* xs = (const u64*)(xbuf + (size_t)(TSTEPS & 1) * NX);
        u64 v8[XW];
        #pragma unroll
        for (int j = 0; j < XW; ++j) v8[j] = ld_agent64(xs + tid + TPB * j);
        u64* xc8 = (u64*)xc;
        #pragma unroll
        for (int j = 0; j < XW; ++j) xc8[tid + TPB * j] = v8[j];
        __syncthreads();
        if (wave == NWAVE - 1) {
            const int lane = tid & 63;
            float a = 0.0f;
            for (int i = lane; i < NX; i += 64) a += woutrow[i] * xc[i];
            #pragma unroll
            for (int off = 32; off; off >>= 1) a += __shfl_down(a, off, 64);
            if (lane == 0) Y[(size_t)(TSTEPS - 1) * NY + wg] = a;
        }
    }
}

extern "C" void kernel_launch(void* const* d_in, const int* in_sizes, int n_in,
                              void* d_out, int out_size, void* d_ws, size_t ws_size,
                              hipStream_t stream) {
    const float* UT   = (const float*)d_in[0];  // [T, NU]
    const float* x0   = (const float*)d_in[1];  // [NX]
    const float* Win  = (const float*)d_in[2];  // [NX, NU]
    const float* W    = (const float*)d_in[3];  // [NX, NX]
    const float* Wout = (const float*)d_in[4];  // [NY, NX]
    float* Y = (float*)d_out;                   // [T*NY]

    char* ws = (char*)d_ws;
    float* xbuf  = (float*)ws;                  // 2*NX fp32 = 32 KB
    int*   flags = (int*)(ws + 32768);          // 64*8 ints = 2 KB
    int2*  ell   = (int2*)(ws + 32768 + 4096);  // NX*CAP*8 = 11,534,336 B

    build_ell_kernel<<<dim3(NX), dim3(256), 0, stream>>>(W, ell, flags);

    void* args[] = { (void*)&UT, (void*)&x0, (void*)&Win, (void*)&Wout,
                     (void*)&ell, (void*)&xbuf, (void*)&flags, (void*)&Y };
    hipLaunchCooperativeKernel((const void*)esn_kernel, dim3(WGS), dim3(TPB),
                               args, 0, stream);
}